// Round 1
// baseline (1510.230 us; speedup 1.0000x reference)
//
#include <hip/hip_runtime.h>
#include <math.h>

#define N_PTS 1048576

typedef _Float16 half8 __attribute__((ext_vector_type(8)));
typedef _Float16 half2v __attribute__((ext_vector_type(2)));
typedef float float4v __attribute__((ext_vector_type(4)));

// ws layout (fp16 element offsets):
//   [0, 24576)        W0T  [256 n][96 k]   (k 91..95 zero-padded)
//   [24576, 483328)   WhT  7 x [256 n][256 k]
//   [483328, 487424)  WheadT [16 n][256 k] (n=0 -> wd, n=1..3 -> wc, rest 0)
#define W0T_OFF 0
#define WHT_OFF 24576
#define WHEAD_OFF 483328
#define WS_HALVES 487424

__global__ void prep_weights(const float* __restrict__ w0,
                             const float* __restrict__ wh,
                             const float* __restrict__ wd,
                             const float* __restrict__ wc,
                             _Float16* __restrict__ ws) {
  int stride = gridDim.x * blockDim.x;
  for (int i = blockIdx.x * blockDim.x + threadIdx.x; i < WS_HALVES; i += stride) {
    float v;
    if (i < WHT_OFF) {                       // W0T [256][96]
      int n = i / 96, k = i - n * 96;
      v = (k < 91) ? w0[k * 256 + n] : 0.0f;
    } else if (i < WHEAD_OFF) {              // WhT 7x[256][256]
      int j = i - WHT_OFF;
      int layer = j >> 16;
      int r = j & 65535;
      int n = r >> 8, k = r & 255;
      v = wh[(layer << 16) + k * 256 + n];
    } else {                                 // WheadT [16][256]
      int j = i - WHEAD_OFF;
      int n = j >> 8, k = j & 255;
      v = (n == 0) ? wd[k] : ((n < 4) ? wc[k * 3 + n - 1] : 0.0f);
    }
    ws[i] = (_Float16)v;
  }
}

// LDS activation buffer: [256 m][256 k] fp16, row = 512 B,
// XOR swizzle on byte-col bits [4:6] by (m&7) to kill column bank conflicts.
__device__ __forceinline__ int xaddr(int m, int kb) {
  return m * 512 + (kb ^ ((m & 7) << 4));
}

__device__ __forceinline__ void sth2(char* X, int m, int k, float a, float b) {
  half2v v;
  v.x = (_Float16)a;
  v.y = (_Float16)b;
  *(half2v*)&X[xaddr(m, k * 2)] = v;
}

// One MLP layer: Y[256 m][256 n] = act(X[256 m][K k] @ W[K][256] + b)
// Wave (wm, wn): rows wm*128..+127, cols wn*64..+63.
// A frag: lane holds A[m = base+(l&15)][k = 8*(l>>4)+j]  (ds_read_b128, swizzled)
// B frag: lane holds B[k = 8*(l>>4)+j][n = base+(l&15)]  (global dwordx4 from W^T)
// D frag: lane holds D[m = base+(l>>4)*4+r][n = base+(l&15)]
template <int K>
__device__ __forceinline__ void mlp_layer(char* X, const _Float16* __restrict__ Wt,
                                          const float* __restrict__ bias, bool relu,
                                          int wm, int wn, int lr, int lg) {
  float4v acc[8][4];
#pragma unroll
  for (int nt = 0; nt < 4; ++nt) {
    float bv = bias[wn * 64 + nt * 16 + lr];
#pragma unroll
    for (int mt = 0; mt < 8; ++mt) acc[mt][nt] = (float4v){bv, bv, bv, bv};
  }
#pragma unroll 2
  for (int ks = 0; ks < K / 32; ++ks) {
    half8 a[8];
#pragma unroll
    for (int mt = 0; mt < 8; ++mt) {
      int m = wm * 128 + mt * 16 + lr;
      a[mt] = *(const half8*)&X[xaddr(m, ks * 64 + lg * 16)];
    }
#pragma unroll
    for (int nt = 0; nt < 4; ++nt) {
      int n = wn * 64 + nt * 16 + lr;
      half8 b = *(const half8*)(Wt + (size_t)n * K + ks * 32 + lg * 8);
#pragma unroll
      for (int mt = 0; mt < 8; ++mt)
        acc[mt][nt] = __builtin_amdgcn_mfma_f32_16x16x32_f16(a[mt], b, acc[mt][nt], 0, 0, 0);
    }
  }
  __syncthreads();  // all waves done READING X
#pragma unroll
  for (int mt = 0; mt < 8; ++mt)
#pragma unroll
    for (int nt = 0; nt < 4; ++nt)
#pragma unroll
      for (int r = 0; r < 4; ++r) {
        float y = acc[mt][nt][r];
        if (relu) y = fmaxf(y, 0.0f);
        int m = wm * 128 + mt * 16 + lg * 4 + r;
        int k = wn * 64 + nt * 16 + lr;
        *(_Float16*)&X[xaddr(m, k * 2)] = (_Float16)y;
      }
  __syncthreads();  // Y visible as next layer's X
}

__global__ __launch_bounds__(512, 2) void nerf_fused(
    const float* __restrict__ pos, const float* __restrict__ vdir,
    const float* __restrict__ t0, const float* __restrict__ t1,
    const float* __restrict__ t2, const float* __restrict__ t3,
    const float* __restrict__ t4, const float* __restrict__ t5,
    const float* __restrict__ t6, const float* __restrict__ t7,
    const float* __restrict__ b0, const float* __restrict__ bh,
    const float* __restrict__ bd, const float* __restrict__ bc,
    const _Float16* __restrict__ ws, float* __restrict__ out) {
  __shared__ __align__(16) char X[131072];  // [256 m][256 k] fp16
  const int tid = threadIdx.x;
  const int wg = blockIdx.x;

  // ---------------- encode: 256 points -> X[m][0..95] ----------------
  if (tid < 256) {
    // hash features, k = 0..63
    const int p = wg * 256 + tid;
    const float px = pos[p * 3], py = pos[p * 3 + 1], pz = pos[p * 3 + 2];
    const float* tabs[8] = {t0, t1, t2, t3, t4, t5, t6, t7};
    const int resi[8] = {32, 64, 128, 256, 512, 1024, 2048, 2048};
    const float tmax[8] = {32767.0f, 262143.0f, 524287.0f, 524287.0f,
                           524287.0f, 524287.0f, 524287.0f, 524287.0f};
#pragma unroll
    for (int lv = 0; lv < 8; ++lv) {
      const float r = (float)resi[lv];
      const float hr = 0.5f * r;
      const float rm1 = r - 1.0f;
      // replicate ref fp32 rounding exactly; NO fma contraction
      float cx = fminf(fmaxf(__fmul_rn(__fadd_rn(px, 1.0f), hr), 0.0f), rm1);
      float cy = fminf(fmaxf(__fmul_rn(__fadd_rn(py, 1.0f), hr), 0.0f), rm1);
      float cz = fminf(fmaxf(__fmul_rn(__fadd_rn(pz, 1.0f), hr), 0.0f), rm1);
      float idxf = __fadd_rn(__fadd_rn(__fmul_rn(cx, r * r), __fmul_rn(cy, r)), cz);
      idxf = fminf(fmaxf(idxf, 0.0f), tmax[lv]);
      int idx = (int)idxf;
      const float4* row = (const float4*)(tabs[lv] + (size_t)idx * 8);
      float4 f0 = row[0], f1 = row[1];
      sth2(X, tid, lv * 8 + 0, f0.x, f0.y);
      sth2(X, tid, lv * 8 + 2, f0.z, f0.w);
      sth2(X, tid, lv * 8 + 4, f1.x, f1.y);
      sth2(X, tid, lv * 8 + 6, f1.z, f1.w);
    }
  } else {
    // view features, k = 64..90, zeros 91..95
    const int m = tid - 256;
    const int p = wg * 256 + m;
    float v0 = vdir[p * 3], v1 = vdir[p * 3 + 1], v2 = vdir[p * 3 + 2];
    const float cf[4] = {(float)(M_PI), (float)(2.0 * M_PI),
                         (float)(4.0 * M_PI), (float)(8.0 * M_PI)};
    float feat[32];
    feat[0] = v0; feat[1] = v1; feat[2] = v2;
    float vv[3] = {v0, v1, v2};
#pragma unroll
    for (int f = 0; f < 4; ++f)
#pragma unroll
      for (int d = 0; d < 3; ++d) {
        float arg = __fmul_rn(cf[f], vv[d]);
        feat[3 + f * 6 + d] = sinf(arg);
        feat[6 + f * 6 + d] = cosf(arg);
      }
#pragma unroll
    for (int i = 27; i < 32; ++i) feat[i] = 0.0f;
#pragma unroll
    for (int i = 0; i < 16; ++i) sth2(X, m, 64 + 2 * i, feat[2 * i], feat[2 * i + 1]);
  }
  __syncthreads();

  // ---------------- MLP ----------------
  const int l = tid & 63;
  const int w = tid >> 6;
  const int wm = w >> 2, wn = w & 3;
  const int lr = l & 15, lg = l >> 4;

  mlp_layer<96>(X, ws + W0T_OFF, b0, true, wm, wn, lr, lg);
#pragma unroll 1
  for (int i = 0; i < 7; ++i)
    mlp_layer<256>(X, ws + WHT_OFF + (i << 16), bh + (i << 8), i < 6, wm, wn, lr, lg);

  // ---------------- head: density + color ----------------
  // each wave takes rows w*32..w*32+31, N-tile of 16 (n=0 density, n=1..3 color)
  float4v hacc[2];
  {
    float bv = (lr == 0) ? bd[0] : ((lr < 4) ? bc[lr - 1] : 0.0f);
    hacc[0] = (float4v){bv, bv, bv, bv};
    hacc[1] = hacc[0];
  }
#pragma unroll
  for (int ks = 0; ks < 8; ++ks) {
    half8 bfr = *(const half8*)(ws + WHEAD_OFF + lr * 256 + ks * 32 + lg * 8);
#pragma unroll
    for (int mt = 0; mt < 2; ++mt) {
      int m = w * 32 + mt * 16 + lr;
      half8 a = *(const half8*)&X[xaddr(m, ks * 64 + lg * 16)];
      hacc[mt] = __builtin_amdgcn_mfma_f32_16x16x32_f16(a, bfr, hacc[mt], 0, 0, 0);
    }
  }
#pragma unroll
  for (int mt = 0; mt < 2; ++mt)
#pragma unroll
    for (int r = 0; r < 4; ++r) {
      int p = wg * 256 + w * 32 + mt * 16 + lg * 4 + r;
      float vv = hacc[mt][r];
      if (lr == 0) {
        out[p] = vv;  // density
      } else if (lr < 4) {
        out[N_PTS + 3 * p + (lr - 1)] = 1.0f / (1.0f + expf(-vv));  // color
      }
    }
}

extern "C" void kernel_launch(void* const* d_in, const int* in_sizes, int n_in,
                              void* d_out, int out_size, void* d_ws, size_t ws_size,
                              hipStream_t stream) {
  const float* pos = (const float*)d_in[0];
  const float* vdir = (const float*)d_in[1];
  const float* t0 = (const float*)d_in[2];
  const float* t1 = (const float*)d_in[3];
  const float* t2 = (const float*)d_in[4];
  const float* t3 = (const float*)d_in[5];
  const float* t4 = (const float*)d_in[6];
  const float* t5 = (const float*)d_in[7];
  const float* t6 = (const float*)d_in[8];
  const float* t7 = (const float*)d_in[9];
  const float* w0 = (const float*)d_in[10];
  const float* b0 = (const float*)d_in[11];
  const float* wh = (const float*)d_in[12];
  const float* bh = (const float*)d_in[13];
  const float* wd = (const float*)d_in[14];
  const float* bd = (const float*)d_in[15];
  const float* wc = (const float*)d_in[16];
  const float* bc = (const float*)d_in[17];
  _Float16* ws = (_Float16*)d_ws;
  float* out = (float*)d_out;

  hipLaunchKernelGGL(prep_weights, dim3((WS_HALVES + 255) / 256), dim3(256), 0, stream,
                     w0, wh, wd, wc, ws);
  hipLaunchKernelGGL(nerf_fused, dim3(N_PTS / 256), dim3(512), 0, stream,
                     pos, vdir, t0, t1, t2, t3, t4, t5, t6, t7,
                     b0, bh, bd, bc, (const _Float16*)ws, out);
}

// Round 2
// 983.422 us; speedup vs baseline: 1.5357x; 1.5357x over previous
//
#include <hip/hip_runtime.h>
#include <math.h>

#define N_PTS 1048576

typedef _Float16 half8 __attribute__((ext_vector_type(8)));
typedef _Float16 half4v __attribute__((ext_vector_type(4)));
typedef float float4v __attribute__((ext_vector_type(4)));
typedef float f32x16 __attribute__((ext_vector_type(16)));

// ws layout (fp16 element offsets), k-tiled for coalesced A-frag loads:
//   W0   [12 kb][256 n][8 j]   k = kb*8+j (91..95 zero)       @ 0       (24576)
//   Wh   7 x [32 kb][256 n][8 j]                              @ 24576   (7*65536)
//   Whead [16 n][256 k] plain  (n=0 -> wd, 1..3 -> wc)        @ 483328  (4096)
#define W0T_OFF 0
#define WHT_OFF 24576
#define WHEAD_OFF 483328
#define WS_HALVES 487424

__global__ void prep_weights(const float* __restrict__ w0,
                             const float* __restrict__ wh,
                             const float* __restrict__ wd,
                             const float* __restrict__ wc,
                             _Float16* __restrict__ ws) {
  int stride = gridDim.x * blockDim.x;
  for (int i = blockIdx.x * blockDim.x + threadIdx.x; i < WS_HALVES; i += stride) {
    float v;
    if (i < WHT_OFF) {                        // W0 tiled [12][256][8]
      int kb = i >> 11, n = (i >> 3) & 255, j = i & 7;
      int k = kb * 8 + j;
      v = (k < 91) ? w0[k * 256 + n] : 0.0f;
    } else if (i < WHEAD_OFF) {               // Wh tiled 7x[32][256][8]
      int rel = i - WHT_OFF;
      int layer = rel >> 16;
      int r = rel & 65535;
      int kb = r >> 11, n = (r >> 3) & 255, j = r & 7;
      int k = kb * 8 + j;
      v = wh[(layer << 16) + k * 256 + n];
    } else {                                  // Whead plain [16][256]
      int rel = i - WHEAD_OFF;
      int n = rel >> 8, k = rel & 255;
      v = (n == 0) ? wd[k] : ((n < 4) ? wc[k * 3 + n - 1] : 0.0f);
    }
    ws[i] = (_Float16)v;
  }
}

// X: [128 m][256 k] fp16, row = 512 B. XOR-swizzle byte-col bits [4:6] by (m&7).
__device__ __forceinline__ int xaddr(int m, int kb) {
  return m * 512 + (kb ^ ((m & 7) << 4));
}

// One layer: for all 128 pts, Y[n] = act(sum_k W[n][k] X[m][k] + b[n]).
// Swapped MFMA: A = weights (rows -> n), B = acts (cols -> m), D[n][m].
// Wave w owns n in [w*32, w*32+32), all 128 m (4 m-tiles of 32).
// A frag: lane holds W[n = w*32 + (l&31)][k = ks*16 + (l>>5)*8 + j]  (coalesced, tiled ws)
// B frag: lane holds X[m = mt*32 + (l&31)][k = ks*16 + (l>>5)*8 + j] (ds_read_b128, swizzled)
// D frag: lane holds D[n = w*32 + 8q + 4*(l>>5) + rr][m = mt*32 + (l&31)], reg = 4q+rr
template <int KB>  // KB = K/16
__device__ __forceinline__ void mlp_layer(char* X, const _Float16* __restrict__ Wt,
                                          const float* __restrict__ bias, bool relu,
                                          int w, int lr5, int lg2) {
  f32x16 acc[4];
#pragma unroll
  for (int mt = 0; mt < 4; ++mt)
#pragma unroll
    for (int r = 0; r < 16; ++r) acc[mt][r] = 0.0f;

  const _Float16* wbase = Wt + ((size_t)(lg2 * 256 + w * 32 + lr5)) * 8;
  const int swz = (lr5 & 7) << 4;
  const int cbase = lg2 * 16;

  half8 a_cur = *(const half8*)wbase;
#pragma unroll
  for (int ks = 0; ks < KB; ++ks) {
    half8 a_nxt = a_cur;
    if (ks + 1 < KB) a_nxt = *(const half8*)(wbase + (size_t)(ks + 1) * 4096);
    const int c = (ks * 32 + cbase) ^ swz;
#pragma unroll
    for (int mt = 0; mt < 4; ++mt) {
      half8 b = *(const half8*)&X[(mt * 32 + lr5) * 512 + c];
      acc[mt] = __builtin_amdgcn_mfma_f32_32x32x16_f16(a_cur, b, acc[mt], 0, 0, 0);
    }
    a_cur = a_nxt;
  }
  __syncthreads();  // all waves done reading X

  const float* bptr = bias + w * 32 + lg2 * 4;
  float4v bq[4];
#pragma unroll
  for (int q = 0; q < 4; ++q) bq[q] = *(const float4v*)(bptr + q * 8);
#pragma unroll
  for (int mt = 0; mt < 4; ++mt) {
    const int rowb = (mt * 32 + lr5) * 512;
#pragma unroll
    for (int q = 0; q < 4; ++q) {
      half4v hv;
#pragma unroll
      for (int rr = 0; rr < 4; ++rr) {
        float y = acc[mt][q * 4 + rr] + bq[q][rr];
        if (relu) y = fmaxf(y, 0.0f);
        hv[rr] = (_Float16)y;
      }
      // n0 = w*32 + q*8 + lg2*4 -> byte col = w*64 + q*16 + lg2*8 (8B aligned; XOR hits bits 4-6)
      *(half4v*)&X[rowb + ((w * 64 + q * 16 + lg2 * 8) ^ swz)] = hv;
    }
  }
  __syncthreads();  // Y visible as next layer's X
}

__global__ __launch_bounds__(512, 4) void nerf_fused(
    const float* __restrict__ pos, const float* __restrict__ vdir,
    const float* __restrict__ t0, const float* __restrict__ t1,
    const float* __restrict__ t2, const float* __restrict__ t3,
    const float* __restrict__ t4, const float* __restrict__ t5,
    const float* __restrict__ t6, const float* __restrict__ t7,
    const float* __restrict__ b0, const float* __restrict__ bh,
    const float* __restrict__ bd, const float* __restrict__ bc,
    const _Float16* __restrict__ ws, float* __restrict__ out) {
  __shared__ __align__(16) char X[65536];  // [128 m][256 k] fp16
  const int tid = threadIdx.x;
  const int wg = blockIdx.x;
  const int m = tid & 127;
  const int part = tid >> 7;
  const int p = wg * 128 + m;

  // ---------------- encode: 128 points -> X[m][0..95] ----------------
  if (part < 3) {
    // hash levels: part0 -> 0,1,2  part1 -> 3,4,5  part2 -> 6,7
    const float px = pos[p * 3], py = pos[p * 3 + 1], pz = pos[p * 3 + 2];
    const float* tabs[8] = {t0, t1, t2, t3, t4, t5, t6, t7};
    const int resi[8] = {32, 64, 128, 256, 512, 1024, 2048, 2048};
    const float tmax[8] = {32767.0f, 262143.0f, 524287.0f, 524287.0f,
                           524287.0f, 524287.0f, 524287.0f, 524287.0f};
    const int lv0 = part * 3;
    const int lv1 = (part == 2) ? 8 : lv0 + 3;
    for (int lv = lv0; lv < lv1; ++lv) {
      const float r = (float)resi[lv];
      const float hr = 0.5f * r;
      const float rm1 = r - 1.0f;
      // replicate numpy fp32 rounding exactly; no FMA contraction
      float cx = fminf(fmaxf(__fmul_rn(__fadd_rn(px, 1.0f), hr), 0.0f), rm1);
      float cy = fminf(fmaxf(__fmul_rn(__fadd_rn(py, 1.0f), hr), 0.0f), rm1);
      float cz = fminf(fmaxf(__fmul_rn(__fadd_rn(pz, 1.0f), hr), 0.0f), rm1);
      float idxf = __fadd_rn(__fadd_rn(__fmul_rn(cx, r * r), __fmul_rn(cy, r)), cz);
      idxf = fminf(fmaxf(idxf, 0.0f), tmax[lv]);
      int idx = (int)idxf;
      const float4* row = (const float4*)(tabs[lv] + (size_t)idx * 8);
      float4 f0 = row[0], f1 = row[1];
      half8 h;
      h[0] = (_Float16)f0.x; h[1] = (_Float16)f0.y;
      h[2] = (_Float16)f0.z; h[3] = (_Float16)f0.w;
      h[4] = (_Float16)f1.x; h[5] = (_Float16)f1.y;
      h[6] = (_Float16)f1.z; h[7] = (_Float16)f1.w;
      *(half8*)&X[xaddr(m, lv * 16)] = h;
    }
  } else {
    // view features k = 64..90, zero pad to 95
    float v0 = vdir[p * 3], v1 = vdir[p * 3 + 1], v2 = vdir[p * 3 + 2];
    const float cf[4] = {(float)(M_PI), (float)(2.0 * M_PI),
                         (float)(4.0 * M_PI), (float)(8.0 * M_PI)};
    float feat[32];
    feat[0] = v0; feat[1] = v1; feat[2] = v2;
    float vv[3] = {v0, v1, v2};
#pragma unroll
    for (int f = 0; f < 4; ++f)
#pragma unroll
      for (int d = 0; d < 3; ++d) {
        float arg = __fmul_rn(cf[f], vv[d]);
        feat[3 + f * 6 + d] = __sinf(arg);
        feat[6 + f * 6 + d] = __cosf(arg);
      }
#pragma unroll
    for (int i = 27; i < 32; ++i) feat[i] = 0.0f;
#pragma unroll
    for (int s = 0; s < 4; ++s) {
      half8 h;
#pragma unroll
      for (int j = 0; j < 8; ++j) h[j] = (_Float16)feat[s * 8 + j];
      *(half8*)&X[xaddr(m, 128 + s * 16)] = h;
    }
  }
  __syncthreads();

  // ---------------- MLP ----------------
  const int lane = tid & 63;
  const int w = tid >> 6;          // wave 0..7 -> n-tile
  const int lr5 = lane & 31;
  const int lg2 = lane >> 5;

  mlp_layer<6>(X, ws + W0T_OFF, b0, true, w, lr5, lg2);
#pragma unroll 1
  for (int i = 0; i < 7; ++i)
    mlp_layer<16>(X, ws + WHT_OFF + (i << 16), bh + (i << 8), i < 6, w, lr5, lg2);

  // ---------------- head (16x16x32, A = acts): wave w -> pts w*16..w*16+15 --------
  const int lr = lane & 15;
  const int lg = lane >> 4;
  float4v hacc;
  {
    float bv = (lr == 0) ? bd[0] : ((lr < 4) ? bc[lr - 1] : 0.0f);
    hacc = (float4v){bv, bv, bv, bv};
  }
  const _Float16* Wh = ws + WHEAD_OFF;
#pragma unroll
  for (int ks = 0; ks < 8; ++ks) {
    half8 bfr = *(const half8*)(Wh + lr * 256 + ks * 32 + lg * 8);
    half8 a = *(const half8*)&X[xaddr(w * 16 + lr, ks * 64 + lg * 16)];
    hacc = __builtin_amdgcn_mfma_f32_16x16x32_f16(a, bfr, hacc, 0, 0, 0);
  }
#pragma unroll
  for (int r = 0; r < 4; ++r) {
    int pp = wg * 128 + w * 16 + lg * 4 + r;
    float vv = hacc[r];
    if (lr == 0) {
      out[pp] = vv;  // density
    } else if (lr < 4) {
      out[N_PTS + 3 * pp + (lr - 1)] = 1.0f / (1.0f + __expf(-vv));  // color
    }
  }
}

extern "C" void kernel_launch(void* const* d_in, const int* in_sizes, int n_in,
                              void* d_out, int out_size, void* d_ws, size_t ws_size,
                              hipStream_t stream) {
  const float* pos = (const float*)d_in[0];
  const float* vdir = (const float*)d_in[1];
  const float* t0 = (const float*)d_in[2];
  const float* t1 = (const float*)d_in[3];
  const float* t2 = (const float*)d_in[4];
  const float* t3 = (const float*)d_in[5];
  const float* t4 = (const float*)d_in[6];
  const float* t5 = (const float*)d_in[7];
  const float* t6 = (const float*)d_in[8];
  const float* t7 = (const float*)d_in[9];
  const float* w0 = (const float*)d_in[10];
  const float* b0 = (const float*)d_in[11];
  const float* wh = (const float*)d_in[12];
  const float* bh = (const float*)d_in[13];
  const float* wd = (const float*)d_in[14];
  const float* bd = (const float*)d_in[15];
  const float* wc = (const float*)d_in[16];
  const float* bc = (const float*)d_in[17];
  _Float16* ws = (_Float16*)d_ws;
  float* out = (float*)d_out;

  hipLaunchKernelGGL(prep_weights, dim3((WS_HALVES + 255) / 256), dim3(256), 0, stream,
                     w0, wh, wd, wc, ws);
  hipLaunchKernelGGL(nerf_fused, dim3(N_PTS / 128), dim3(512), 0, stream,
                     pos, vdir, t0, t1, t2, t3, t4, t5, t6, t7,
                     b0, bh, bd, bc, (const _Float16*)ws, out);
}